// Round 4
// baseline (596.688 us; speedup 1.0000x reference)
//
#include <hip/hip_runtime.h>
#include <stdint.h>

typedef unsigned short u16;
typedef __bf16 bf16x8 __attribute__((ext_vector_type(8)));
typedef float f32x4 __attribute__((ext_vector_type(4)));

#define DEVINL static __device__ __forceinline__

// fp32 -> bf16 round-to-nearest-even
DEVINL u16 f2bf(float f) {
  uint32_t u = __builtin_bit_cast(uint32_t, f);
  u += 0x7fffu + ((u >> 16) & 1u);
  return (u16)(u >> 16);
}

// pack two fp32 -> bf16x2 dword (round-half-up: +0x8000 then take hi16)
DEVINL uint32_t pack_bf2(float f0, float f1) {
  uint32_t u0 = __builtin_bit_cast(uint32_t, f0) + 0x8000u;
  uint32_t u1 = __builtin_bit_cast(uint32_t, f1) + 0x8000u;
  return __builtin_amdgcn_perm(u1, u0, 0x07060302u);  // [u1.hi16, u0.hi16]
}

DEVINL bf16x8 ld_frag(const u16* p) { return *(const bf16x8*)p; }

DEVINL void gld_lds16(const void* g, void* l) {
  __builtin_amdgcn_global_load_lds((const __attribute__((address_space(1))) void*)g,
                                   (__attribute__((address_space(3))) void*)l, 16, 0, 0);
}

// ---------------------------------------------------------------------------
// Weight convert+transpose: W fp32 (K,N) row-major -> Wt bf16 (N,K) row-major
// ---------------------------------------------------------------------------
__global__ __launch_bounds__(256)
void transpose_bf16(const float* __restrict__ W, u16* __restrict__ Wt, int K, int N) {
  __shared__ float tile[32][33];
  const int n0 = blockIdx.x * 32, k0 = blockIdx.y * 32;
  const int tx = threadIdx.x, ty = threadIdx.y;  // (32,8)
#pragma unroll
  for (int i = 0; i < 32; i += 8)
    tile[ty + i][tx] = W[(size_t)(k0 + ty + i) * N + n0 + tx];
  __syncthreads();
#pragma unroll
  for (int i = 0; i < 32; i += 8)
    Wt[(size_t)(n0 + ty + i) * K + k0 + tx] = f2bf(tile[tx][ty + i]);
}

// ---------------------------------------------------------------------------
// LayerNorm: fp32 (rows,1024) -> bf16, single pass (E[x^2]-mu^2), eps=1e-5
// ---------------------------------------------------------------------------
__global__ __launch_bounds__(256)
void ln_kernel(const float* __restrict__ x, const float* __restrict__ g,
               const float* __restrict__ b, u16* __restrict__ out) {
  __shared__ float red[8];
  const size_t row = blockIdx.x;
  const int tid = threadIdx.x;
  float4 v = ((const float4*)(x + row * 1024))[tid];
  float s = v.x + v.y + v.z + v.w;
  float s2 = v.x * v.x + v.y * v.y + v.z * v.z + v.w * v.w;
#pragma unroll
  for (int o = 32; o; o >>= 1) { s += __shfl_down(s, o); s2 += __shfl_down(s2, o); }
  const int w = tid >> 6;
  if ((tid & 63) == 0) { red[w * 2] = s; red[w * 2 + 1] = s2; }
  __syncthreads();
  const float S = red[0] + red[2] + red[4] + red[6];
  const float S2 = red[1] + red[3] + red[5] + red[7];
  const float mu = S * (1.f / 1024.f);
  const float var = S2 * (1.f / 1024.f) - mu * mu;
  const float rstd = rsqrtf(var + 1e-5f);
  float4 gv = ((const float4*)g)[tid];
  float4 bv = ((const float4*)b)[tid];
  ushort4 o;
  o.x = f2bf((v.x - mu) * rstd * gv.x + bv.x);
  o.y = f2bf((v.y - mu) * rstd * gv.y + bv.y);
  o.z = f2bf((v.z - mu) * rstd * gv.z + bv.z);
  o.w = f2bf((v.w - mu) * rstd * gv.w + bv.w);
  ((ushort4*)(out + row * 1024))[tid] = o;
}

// ---------------------------------------------------------------------------
// GEMM: C(M,N) = A(M,K) bf16 @ Bt(N,K)^T bf16, fp32 acc, fused epilogues.
// 128x128 tile, BK=32, 4 waves (2x2 of 64x64), 16x16x32 MFMA, global_load_lds.
// Split-K via gridDim.z (EPI_ADD only: atomicAdd fp32; bias added by z==0).
// ---------------------------------------------------------------------------
enum { EPI_KQV = 0, EPI_RESID = 1, EPI_GELU = 2, EPI_ADD = 3 };

template <int EPI>
__global__ __launch_bounds__(256)
void gemm_kernel(const u16* __restrict__ A, const u16* __restrict__ Bt,
                 const float* __restrict__ bias, void* __restrict__ outp,
                 const float* __restrict__ resid, int M, int N, int K) {
  __shared__ alignas(16) u16 sA[128 * 32];
  __shared__ alignas(16) u16 sB[128 * 32];
  const int tid = threadIdx.x;
  const int w = tid >> 6, l = tid & 63;
  const int q4 = l >> 4, c = l & 15;
  const int tm = blockIdx.y * 128, tn = blockIdx.x * 128;
  const int mh = (w >> 1) * 64, nh = (w & 1) * 64;
  // split-K range (gridDim.z splits; kslice multiple of 32)
  const int kslice = K / (int)gridDim.z;
  const int kbeg = (int)blockIdx.z * kslice, kend = kbeg + kslice;

  f32x4 acc[4][4] = {};

  // staging: 8 chunks of 1KB each (16 rows x 32 cols); wave w owns chunks 2w,2w+1
  const int srow = l >> 2;           // 0..15 row within chunk
  const int scol = (l & 3) * 8;      // elem col within row
  const u16* gA0 = A + (size_t)(tm + (w * 2) * 16 + srow) * K + scol;
  const u16* gA1 = A + (size_t)(tm + (w * 2 + 1) * 16 + srow) * K + scol;
  const u16* gB0 = Bt + (size_t)(tn + (w * 2) * 16 + srow) * K + scol;
  const u16* gB1 = Bt + (size_t)(tn + (w * 2 + 1) * 16 + srow) * K + scol;
  u16* lA0 = sA + (w * 2) * 512;
  u16* lA1 = sA + (w * 2 + 1) * 512;
  u16* lB0 = sB + (w * 2) * 512;
  u16* lB1 = sB + (w * 2 + 1) * 512;

  for (int k0 = kbeg; k0 < kend; k0 += 32) {
    __syncthreads();  // prior reads done before overwrite
    gld_lds16(gA0 + k0, lA0);
    gld_lds16(gA1 + k0, lA1);
    gld_lds16(gB0 + k0, lB0);
    gld_lds16(gB1 + k0, lB1);
    asm volatile("s_waitcnt vmcnt(0)" ::: "memory");
    __syncthreads();
    bf16x8 af[4], bfv[4];
#pragma unroll
    for (int mt = 0; mt < 4; ++mt) af[mt] = ld_frag(sA + (mh + mt * 16 + c) * 32 + q4 * 8);
#pragma unroll
    for (int nt = 0; nt < 4; ++nt) bfv[nt] = ld_frag(sB + (nh + nt * 16 + c) * 32 + q4 * 8);
#pragma unroll
    for (int mt = 0; mt < 4; ++mt)
#pragma unroll
      for (int nt = 0; nt < 4; ++nt)
        acc[mt][nt] = __builtin_amdgcn_mfma_f32_16x16x32_bf16(af[mt], bfv[nt], acc[mt][nt], 0, 0, 0);
  }

  // epilogue: C row = tm+mh+mt*16+q4*4+reg, col = tn+nh+nt*16+c
#pragma unroll
  for (int mt = 0; mt < 4; ++mt) {
#pragma unroll
    for (int nt = 0; nt < 4; ++nt) {
      const int col = tn + nh + nt * 16 + c;
      const float bcol = (EPI == EPI_ADD && blockIdx.z != 0) ? 0.f : bias[col];
#pragma unroll
      for (int rg = 0; rg < 4; ++rg) {
        const int row = tm + mh + mt * 16 + q4 * 4 + rg;
        float val = acc[mt][nt][rg] + bcol;
        if constexpr (EPI == EPI_KQV) {
          // scatter to per-head layout [b,h][s][...]; s: 0=k (flash-Q, pre-scaled
          // by 0.125*log2e for exp2-domain softmax), 1=q (t,d), 2=v stored (d,t)
          const int bb = row >> 10, t = row & 1023;
          const int s = col >> 10, rem = col & 1023;
          const int hh = rem >> 6, d = rem & 63;
          if (s == 0) val *= 0.18033688011112042f;  // 0.125 * log2(e)
          const size_t base = ((size_t)((bb * 16 + hh) * 3 + s)) << 16;
          const size_t idx = (s == 2) ? base + (size_t)d * 1024 + t : base + (size_t)t * 64 + d;
          ((u16*)outp)[idx] = f2bf(val);
        } else if constexpr (EPI == EPI_RESID) {
          const size_t idx = (size_t)row * 1024 + col;
          ((float*)outp)[idx] = val + resid[idx];
        } else if constexpr (EPI == EPI_GELU) {
          // tanh-approx GELU via single exp2: x*sigmoid(1.5957691(x+0.044715x^3))
          const float x2 = val * val;
          const float t = __builtin_fmaf(x2, -0.102952445f, -2.30221235f);  // *log2e folded
          const float e = __builtin_amdgcn_exp2f(val * t);
          const float ge = val * __builtin_amdgcn_rcpf(1.0f + e);
          ((u16*)outp)[(size_t)row * N + col] = f2bf(ge);
        } else {  // EPI_ADD: split-K partial -> atomic accumulate into fp32 out
          const size_t idx = (size_t)row * 1024 + col;
          atomicAdd(&((float*)outp)[idx], val);
        }
      }
    }
  }
}

// ---------------------------------------------------------------------------
// Flash attention, causal, fixed-max softmax in exp2 domain.
// Computes S^T = fK_tile @ fQ_tile^T and O^T = V^T_tile @ P^T so each lane owns
// one full i-row (i = w*16 + c): per-lane scalar lsum, j-contiguous P writes
// (ds_write_b64), no online-max machinery, no P barrier (wave-private rows).
// Roles: flash-Q = reference k (s=0, pre-scaled), flash-K = q (s=1), V = s=2 (D,T).
// ---------------------------------------------------------------------------
__global__ __launch_bounds__(256)
void attn_kernel(const u16* __restrict__ kqv, u16* __restrict__ outp) {
  constexpr int LS = 72;  // padded stride: 144B rows, 16B aligned, 2-way max conflicts
  __shared__ alignas(16) u16 sP[64 * LS];  // holds Q tile at start, then P (aliased)
  __shared__ alignas(16) u16 sK[64 * LS];
  __shared__ alignas(16) u16 sV[64 * LS];  // V^T tile: row=d, col=j
  const int bh = blockIdx.x;
  const int it = (int)gridDim.y - 1 - (int)blockIdx.y;  // longest blocks dispatch first
  const int tid = threadIdx.x;
  const int w = tid >> 6, l = tid & 63, q4 = l >> 4, c = l & 15;
  const int il = w * 16 + c;  // this lane's i-row within the 64-row tile
  const size_t hb = (size_t)bh * 3 * 65536;
  const u16* qbase = kqv + hb;               // flash-Q (T,D), pre-scaled
  const u16* kbase = kqv + hb + 65536;       // flash-K (T,D)
  const u16* vbase = kqv + hb + 2 * 65536;   // V^T (D,T)

  // stage Q tile into sP (aliased; consumed once after first barrier)
  const int sr = tid >> 3, sc = (tid & 7) * 8;        // staging row/col A
  const int sr2 = sr + 32;                            // staging row B
  *(int4*)&sP[sr * LS + sc] = *(const int4*)(qbase + (size_t)(it * 64 + sr) * 64 + sc);
  *(int4*)&sP[sr2 * LS + sc] = *(const int4*)(qbase + (size_t)(it * 64 + sr2) * 64 + sc);

  f32x4 oacc[4] = {};   // O^T: oacc[dt][rg] = O[i=il][d=dt*16+q4*4+rg]
  float lsum = 0.f;     // per-lane partial row-sum for row i=il
  bf16x8 bq0, bq1;      // loop-invariant Q B-frags

  for (int jt = 0; jt <= it; ++jt) {
    if (jt) __syncthreads();  // prior iter's sK/sV reads done before overwrite
    *(int4*)&sK[sr * LS + sc] = *(const int4*)(kbase + (size_t)(jt * 64 + sr) * 64 + sc);
    *(int4*)&sK[sr2 * LS + sc] = *(const int4*)(kbase + (size_t)(jt * 64 + sr2) * 64 + sc);
    *(int4*)&sV[sr * LS + sc] = *(const int4*)(vbase + (size_t)sr * 1024 + jt * 64 + sc);
    *(int4*)&sV[sr2 * LS + sc] = *(const int4*)(vbase + (size_t)sr2 * 1024 + jt * 64 + sc);
    __syncthreads();
    if (jt == 0) {  // Q frags: B[k=d][n=i]: lane reads fQ[i=il][d=q4*8..]
      bq0 = ld_frag(sP + il * LS + q4 * 8);
      bq1 = ld_frag(sP + il * LS + 32 + q4 * 8);
    }

    // S^T = fK @ fQ^T: st[nt] row j=nt*16+q4*4+rg, col i=il (values in log2 domain)
    f32x4 st[4] = {};
#pragma unroll
    for (int nt = 0; nt < 4; ++nt) {
      st[nt] = __builtin_amdgcn_mfma_f32_16x16x32_bf16(
          ld_frag(sK + (nt * 16 + c) * LS + q4 * 8), bq0, st[nt], 0, 0, 0);
      st[nt] = __builtin_amdgcn_mfma_f32_16x16x32_bf16(
          ld_frag(sK + (nt * 16 + c) * LS + 32 + q4 * 8), bq1, st[nt], 0, 0, 0);
    }

    // softmax numerators + P write (rows wave-private; no barrier needed)
    const bool diag = (jt == it);
    u16* prow = sP + il * LS;
#pragma unroll
    for (int nt = 0; nt < 4; ++nt) {
      float e0 = __builtin_amdgcn_exp2f(st[nt][0]);
      float e1 = __builtin_amdgcn_exp2f(st[nt][1]);
      float e2 = __builtin_amdgcn_exp2f(st[nt][2]);
      float e3 = __builtin_amdgcn_exp2f(st[nt][3]);
      if (diag) {  // mask j > i: j = nt*16+q4*4+rg, i = il = w*16+c
        const int jb = nt * 16 + q4 * 4;
        e0 = (jb + 0 > il) ? 0.f : e0;
        e1 = (jb + 1 > il) ? 0.f : e1;
        e2 = (jb + 2 > il) ? 0.f : e2;
        e3 = (jb + 3 > il) ? 0.f : e3;
      }
      lsum += (e0 + e1) + (e2 + e3);
      uint2 pk = {pack_bf2(e0, e1), pack_bf2(e2, e3)};
      *(uint2*)&prow[nt * 16 + q4 * 4] = pk;
    }

    // O^T += V^T @ P^T: A = V^T-frag (sV row d), B = P-frag (sP row i=il)
    bf16x8 bp0 = ld_frag(sP + il * LS + q4 * 8);
    bf16x8 bp1 = ld_frag(sP + il * LS + 32 + q4 * 8);
#pragma unroll
    for (int dt = 0; dt < 4; ++dt) {
      oacc[dt] = __builtin_amdgcn_mfma_f32_16x16x32_bf16(
          ld_frag(sV + (dt * 16 + c) * LS + q4 * 8), bp0, oacc[dt], 0, 0, 0);
      oacc[dt] = __builtin_amdgcn_mfma_f32_16x16x32_bf16(
          ld_frag(sV + (dt * 16 + c) * LS + 32 + q4 * 8), bp1, oacc[dt], 0, 0, 0);
    }
  }

  // full row sum for i = il: reduce across the 4 q4-groups (lanes c, c+16, c+32, c+48)
  lsum += __shfl_xor(lsum, 16);
  lsum += __shfl_xor(lsum, 32);
  const float linv = 1.f / lsum;

  // write out[b, t=it*64+il, h*64 + dt*16+q4*4+rg] bf16, packed b64 stores
  const int b_ = bh >> 4, h_ = bh & 15;
  const int t_ = it * 64 + il;
  u16* orow = outp + ((size_t)(b_ * 1024 + t_)) * 1024 + h_ * 64;
#pragma unroll
  for (int dt = 0; dt < 4; ++dt) {
    uint2 ok = {pack_bf2(oacc[dt][0] * linv, oacc[dt][1] * linv),
                pack_bf2(oacc[dt][2] * linv, oacc[dt][3] * linv)};
    *(uint2*)&orow[dt * 16 + q4 * 4] = ok;
  }
}

// ---------------------------------------------------------------------------
// Launch
// ---------------------------------------------------------------------------
extern "C" void kernel_launch(void* const* d_in, const int* in_sizes, int n_in,
                              void* d_out, int out_size, void* d_ws, size_t ws_size,
                              hipStream_t stream) {
  const float* x       = (const float*)d_in[0];
  const float* ln1_g   = (const float*)d_in[1];
  const float* ln1_b   = (const float*)d_in[2];
  const float* attn_w  = (const float*)d_in[3];
  const float* attn_b  = (const float*)d_in[4];
  const float* attn_pw = (const float*)d_in[5];
  const float* attn_pb = (const float*)d_in[6];
  const float* ln2_g   = (const float*)d_in[7];
  const float* ln2_b   = (const float*)d_in[8];
  const float* fc_w    = (const float*)d_in[9];
  const float* fc_b    = (const float*)d_in[10];
  const float* mlp_w   = (const float*)d_in[11];
  const float* mlp_b   = (const float*)d_in[12];
  float* out = (float*)d_out;

  // workspace layout (bf16 elements)
  u16* ws = (u16*)d_ws;
  u16* attn_wT  = ws;                         // 3072*1024
  u16* attn_pwT = attn_wT + 3072 * 1024;      // 1024*1024
  u16* fcT      = attn_pwT + 1024 * 1024;     // 4096*1024
  u16* mlpT     = fcT + 4096 * 1024;          // 1024*4096
  u16* hbuf     = mlpT + 1024 * 4096;         // 8192*1024
  u16* kqv      = hbuf + 8192 * 1024;         // 8192*3072 (per-head layout)
  u16* attn_o   = kqv + (size_t)8192 * 3072;  // 8192*1024
  u16* mbuf     = kqv;                        // 8192*4096 (reuses kqv+attn_o)

  dim3 tb(32, 8);
  transpose_bf16<<<dim3(96, 32),  tb, 0, stream>>>(attn_w,  attn_wT,  1024, 3072);
  transpose_bf16<<<dim3(32, 32),  tb, 0, stream>>>(attn_pw, attn_pwT, 1024, 1024);
  transpose_bf16<<<dim3(128, 32), tb, 0, stream>>>(fc_w,    fcT,      1024, 4096);
  transpose_bf16<<<dim3(32, 128), tb, 0, stream>>>(mlp_w,   mlpT,     4096, 1024);

  ln_kernel<<<8192, 256, 0, stream>>>(x, ln1_g, ln1_b, hbuf);

  gemm_kernel<EPI_KQV><<<dim3(24, 64), 256, 0, stream>>>(hbuf, attn_wT, attn_b, kqv,
                                                         nullptr, 8192, 3072, 1024);

  attn_kernel<<<dim3(128, 16), 256, 0, stream>>>(kqv, attn_o);

  gemm_kernel<EPI_RESID><<<dim3(8, 64), 256, 0, stream>>>(attn_o, attn_pwT, attn_pb, out,
                                                          x, 8192, 1024, 1024);

  ln_kernel<<<8192, 256, 0, stream>>>(out, ln2_g, ln2_b, hbuf);

  gemm_kernel<EPI_GELU><<<dim3(32, 64), 256, 0, stream>>>(hbuf, fcT, fc_b, mbuf,
                                                          nullptr, 8192, 4096, 1024);

  // split-K=4: 2048 blocks (vs 512) to hide the per-iter barrier drain;
  // each z-slice covers K=1024, partials accumulated via fp32 atomicAdd.
  gemm_kernel<EPI_ADD><<<dim3(8, 64, 4), 256, 0, stream>>>(mbuf, mlpT, mlp_b, out,
                                                           nullptr, 8192, 1024, 4096);
}

// Round 5
// 575.412 us; speedup vs baseline: 1.0370x; 1.0370x over previous
//
#include <hip/hip_runtime.h>
#include <stdint.h>

typedef unsigned short u16;
typedef __bf16 bf16x8 __attribute__((ext_vector_type(8)));
typedef float f32x4 __attribute__((ext_vector_type(4)));

#define DEVINL static __device__ __forceinline__

// fp32 -> bf16 round-to-nearest-even
DEVINL u16 f2bf(float f) {
  uint32_t u = __builtin_bit_cast(uint32_t, f);
  u += 0x7fffu + ((u >> 16) & 1u);
  return (u16)(u >> 16);
}

// pack two fp32 -> bf16x2 dword (round-half-up: +0x8000 then take hi16)
DEVINL uint32_t pack_bf2(float f0, float f1) {
  uint32_t u0 = __builtin_bit_cast(uint32_t, f0) + 0x8000u;
  uint32_t u1 = __builtin_bit_cast(uint32_t, f1) + 0x8000u;
  return __builtin_amdgcn_perm(u1, u0, 0x07060302u);  // [u1.hi16, u0.hi16]
}

DEVINL bf16x8 ld_frag(const u16* p) { return *(const bf16x8*)p; }

DEVINL void gld_lds16(const void* g, void* l) {
  __builtin_amdgcn_global_load_lds((const __attribute__((address_space(1))) void*)g,
                                   (__attribute__((address_space(3))) void*)l, 16, 0, 0);
}

// ---------------------------------------------------------------------------
// Weight convert+transpose: W fp32 (K,N) row-major -> Wt bf16 (N,K) row-major
// ---------------------------------------------------------------------------
__global__ __launch_bounds__(256)
void transpose_bf16(const float* __restrict__ W, u16* __restrict__ Wt, int K, int N) {
  __shared__ float tile[32][33];
  const int n0 = blockIdx.x * 32, k0 = blockIdx.y * 32;
  const int tx = threadIdx.x, ty = threadIdx.y;  // (32,8)
#pragma unroll
  for (int i = 0; i < 32; i += 8)
    tile[ty + i][tx] = W[(size_t)(k0 + ty + i) * N + n0 + tx];
  __syncthreads();
#pragma unroll
  for (int i = 0; i < 32; i += 8)
    Wt[(size_t)(n0 + ty + i) * K + k0 + tx] = f2bf(tile[tx][ty + i]);
}

// ---------------------------------------------------------------------------
// LayerNorm: fp32 (rows,1024) -> bf16, single pass (E[x^2]-mu^2), eps=1e-5
// ---------------------------------------------------------------------------
__global__ __launch_bounds__(256)
void ln_kernel(const float* __restrict__ x, const float* __restrict__ g,
               const float* __restrict__ b, u16* __restrict__ out) {
  __shared__ float red[8];
  const size_t row = blockIdx.x;
  const int tid = threadIdx.x;
  float4 v = ((const float4*)(x + row * 1024))[tid];
  float s = v.x + v.y + v.z + v.w;
  float s2 = v.x * v.x + v.y * v.y + v.z * v.z + v.w * v.w;
#pragma unroll
  for (int o = 32; o; o >>= 1) { s += __shfl_down(s, o); s2 += __shfl_down(s2, o); }
  const int w = tid >> 6;
  if ((tid & 63) == 0) { red[w * 2] = s; red[w * 2 + 1] = s2; }
  __syncthreads();
  const float S = red[0] + red[2] + red[4] + red[6];
  const float S2 = red[1] + red[3] + red[5] + red[7];
  const float mu = S * (1.f / 1024.f);
  const float var = S2 * (1.f / 1024.f) - mu * mu;
  const float rstd = rsqrtf(var + 1e-5f);
  float4 gv = ((const float4*)g)[tid];
  float4 bv = ((const float4*)b)[tid];
  ushort4 o;
  o.x = f2bf((v.x - mu) * rstd * gv.x + bv.x);
  o.y = f2bf((v.y - mu) * rstd * gv.y + bv.y);
  o.z = f2bf((v.z - mu) * rstd * gv.z + bv.z);
  o.w = f2bf((v.w - mu) * rstd * gv.w + bv.w);
  ((ushort4*)(out + row * 1024))[tid] = o;
}

// ---------------------------------------------------------------------------
// out[i] += partial[i], float4-vectorized (split-K merge)
// ---------------------------------------------------------------------------
__global__ __launch_bounds__(256)
void add_partial(float* __restrict__ out, const float* __restrict__ p) {
  const size_t i = ((size_t)blockIdx.x * 256 + threadIdx.x) * 4;
  float4 o = *(const float4*)(out + i);
  const float4 v = *(const float4*)(p + i);
  o.x += v.x; o.y += v.y; o.z += v.z; o.w += v.w;
  *(float4*)(out + i) = o;
}

// ---------------------------------------------------------------------------
// GEMM: C(M,N) = A(M,K) bf16 @ Bt(N,K)^T bf16, fp32 acc, fused epilogues.
// 128x128 tile, BK=32, 4 waves (2x2 of 64x64), 16x16x32 MFMA, global_load_lds.
// EPI_ADD: split-K=2 via gridDim.z — z0 RMWs out (+bias), z1 stores fp32
// partial (plain coalesced stores, no atomics); merged by add_partial.
// ---------------------------------------------------------------------------
enum { EPI_KQV = 0, EPI_RESID = 1, EPI_GELU = 2, EPI_ADD = 3 };

template <int EPI>
__global__ __launch_bounds__(256)
void gemm_kernel(const u16* __restrict__ A, const u16* __restrict__ Bt,
                 const float* __restrict__ bias, void* __restrict__ outp,
                 const float* __restrict__ resid, int M, int N, int K) {
  __shared__ alignas(16) u16 sA[128 * 32];
  __shared__ alignas(16) u16 sB[128 * 32];
  const int tid = threadIdx.x;
  const int w = tid >> 6, l = tid & 63;
  const int q4 = l >> 4, c = l & 15;
  const int tm = blockIdx.y * 128, tn = blockIdx.x * 128;
  const int mh = (w >> 1) * 64, nh = (w & 1) * 64;
  // split-K range (gridDim.z splits; kslice multiple of 32)
  const int kslice = K / (int)gridDim.z;
  const int kbeg = (int)blockIdx.z * kslice, kend = kbeg + kslice;

  f32x4 acc[4][4] = {};

  // staging: 8 chunks of 1KB each (16 rows x 32 cols); wave w owns chunks 2w,2w+1
  const int srow = l >> 2;           // 0..15 row within chunk
  const int scol = (l & 3) * 8;      // elem col within row
  const u16* gA0 = A + (size_t)(tm + (w * 2) * 16 + srow) * K + scol;
  const u16* gA1 = A + (size_t)(tm + (w * 2 + 1) * 16 + srow) * K + scol;
  const u16* gB0 = Bt + (size_t)(tn + (w * 2) * 16 + srow) * K + scol;
  const u16* gB1 = Bt + (size_t)(tn + (w * 2 + 1) * 16 + srow) * K + scol;
  u16* lA0 = sA + (w * 2) * 512;
  u16* lA1 = sA + (w * 2 + 1) * 512;
  u16* lB0 = sB + (w * 2) * 512;
  u16* lB1 = sB + (w * 2 + 1) * 512;

  for (int k0 = kbeg; k0 < kend; k0 += 32) {
    __syncthreads();  // prior reads done before overwrite
    gld_lds16(gA0 + k0, lA0);
    gld_lds16(gA1 + k0, lA1);
    gld_lds16(gB0 + k0, lB0);
    gld_lds16(gB1 + k0, lB1);
    asm volatile("s_waitcnt vmcnt(0)" ::: "memory");
    __syncthreads();
    bf16x8 af[4], bfv[4];
#pragma unroll
    for (int mt = 0; mt < 4; ++mt) af[mt] = ld_frag(sA + (mh + mt * 16 + c) * 32 + q4 * 8);
#pragma unroll
    for (int nt = 0; nt < 4; ++nt) bfv[nt] = ld_frag(sB + (nh + nt * 16 + c) * 32 + q4 * 8);
#pragma unroll
    for (int mt = 0; mt < 4; ++mt)
#pragma unroll
      for (int nt = 0; nt < 4; ++nt)
        acc[mt][nt] = __builtin_amdgcn_mfma_f32_16x16x32_bf16(af[mt], bfv[nt], acc[mt][nt], 0, 0, 0);
  }

  // epilogue: C row = tm+mh+mt*16+q4*4+reg, col = tn+nh+nt*16+c
#pragma unroll
  for (int mt = 0; mt < 4; ++mt) {
#pragma unroll
    for (int nt = 0; nt < 4; ++nt) {
      const int col = tn + nh + nt * 16 + c;
      const float bcol = (EPI == EPI_ADD && blockIdx.z != 0) ? 0.f : bias[col];
#pragma unroll
      for (int rg = 0; rg < 4; ++rg) {
        const int row = tm + mh + mt * 16 + q4 * 4 + rg;
        float val = acc[mt][nt][rg] + bcol;
        if constexpr (EPI == EPI_KQV) {
          // scatter to per-head layout [b,h][s][...]; s: 0=k (flash-Q, pre-scaled
          // by 0.125*log2e for exp2-domain softmax), 1=q (t,d), 2=v stored (d,t)
          const int bb = row >> 10, t = row & 1023;
          const int s = col >> 10, rem = col & 1023;
          const int hh = rem >> 6, d = rem & 63;
          if (s == 0) val *= 0.18033688011112042f;  // 0.125 * log2(e)
          const size_t base = ((size_t)((bb * 16 + hh) * 3 + s)) << 16;
          const size_t idx = (s == 2) ? base + (size_t)d * 1024 + t : base + (size_t)t * 64 + d;
          ((u16*)outp)[idx] = f2bf(val);
        } else if constexpr (EPI == EPI_RESID) {
          const size_t idx = (size_t)row * 1024 + col;
          ((float*)outp)[idx] = val + resid[idx];
        } else if constexpr (EPI == EPI_GELU) {
          // tanh-approx GELU via single exp2: x*sigmoid(1.5957691(x+0.044715x^3))
          const float x2 = val * val;
          const float t = __builtin_fmaf(x2, -0.102952445f, -2.30221235f);  // *log2e folded
          const float e = __builtin_amdgcn_exp2f(val * t);
          const float ge = val * __builtin_amdgcn_rcpf(1.0f + e);
          ((u16*)outp)[(size_t)row * N + col] = f2bf(ge);
        } else {  // EPI_ADD split-K=2: z0 RMWs out (sole writer), z1 stores partial
          const size_t idx = (size_t)row * 1024 + col;
          if (blockIdx.z == 0) ((float*)outp)[idx] += val;
          else ((float*)resid)[idx] = val;  // resid param carries partial ptr
        }
      }
    }
  }
}

// ---------------------------------------------------------------------------
// Flash attention, causal, fixed-max softmax in exp2 domain.
// Computes S^T = fK_tile @ fQ_tile^T and O^T = V^T_tile @ P^T so each lane owns
// one full i-row (i = w*16 + c): per-lane scalar lsum, j-contiguous P writes
// (ds_write_b64), no online-max machinery, no P barrier (wave-private rows).
// Roles: flash-Q = reference k (s=0, pre-scaled), flash-K = q (s=1), V = s=2 (D,T).
// ---------------------------------------------------------------------------
__global__ __launch_bounds__(256)
void attn_kernel(const u16* __restrict__ kqv, u16* __restrict__ outp) {
  constexpr int LS = 72;  // padded stride: 144B rows, 16B aligned, 2-way max conflicts
  __shared__ alignas(16) u16 sP[64 * LS];  // holds Q tile at start, then P (aliased)
  __shared__ alignas(16) u16 sK[64 * LS];
  __shared__ alignas(16) u16 sV[64 * LS];  // V^T tile: row=d, col=j
  const int bh = blockIdx.x;
  const int it = (int)gridDim.y - 1 - (int)blockIdx.y;  // longest blocks dispatch first
  const int tid = threadIdx.x;
  const int w = tid >> 6, l = tid & 63, q4 = l >> 4, c = l & 15;
  const int il = w * 16 + c;  // this lane's i-row within the 64-row tile
  const size_t hb = (size_t)bh * 3 * 65536;
  const u16* qbase = kqv + hb;               // flash-Q (T,D), pre-scaled
  const u16* kbase = kqv + hb + 65536;       // flash-K (T,D)
  const u16* vbase = kqv + hb + 2 * 65536;   // V^T (D,T)

  // stage Q tile into sP (aliased; consumed once after first barrier)
  const int sr = tid >> 3, sc = (tid & 7) * 8;        // staging row/col A
  const int sr2 = sr + 32;                            // staging row B
  *(int4*)&sP[sr * LS + sc] = *(const int4*)(qbase + (size_t)(it * 64 + sr) * 64 + sc);
  *(int4*)&sP[sr2 * LS + sc] = *(const int4*)(qbase + (size_t)(it * 64 + sr2) * 64 + sc);

  f32x4 oacc[4] = {};   // O^T: oacc[dt][rg] = O[i=il][d=dt*16+q4*4+rg]
  float lsum = 0.f;     // per-lane partial row-sum for row i=il
  bf16x8 bq0, bq1;      // loop-invariant Q B-frags

  for (int jt = 0; jt <= it; ++jt) {
    if (jt) __syncthreads();  // prior iter's sK/sV reads done before overwrite
    *(int4*)&sK[sr * LS + sc] = *(const int4*)(kbase + (size_t)(jt * 64 + sr) * 64 + sc);
    *(int4*)&sK[sr2 * LS + sc] = *(const int4*)(kbase + (size_t)(jt * 64 + sr2) * 64 + sc);
    *(int4*)&sV[sr * LS + sc] = *(const int4*)(vbase + (size_t)sr * 1024 + jt * 64 + sc);
    *(int4*)&sV[sr2 * LS + sc] = *(const int4*)(vbase + (size_t)sr2 * 1024 + jt * 64 + sc);
    __syncthreads();
    if (jt == 0) {  // Q frags: B[k=d][n=i]: lane reads fQ[i=il][d=q4*8..]
      bq0 = ld_frag(sP + il * LS + q4 * 8);
      bq1 = ld_frag(sP + il * LS + 32 + q4 * 8);
    }

    // S^T = fK @ fQ^T: st[nt] row j=nt*16+q4*4+rg, col i=il (values in log2 domain)
    f32x4 st[4] = {};
#pragma unroll
    for (int nt = 0; nt < 4; ++nt) {
      st[nt] = __builtin_amdgcn_mfma_f32_16x16x32_bf16(
          ld_frag(sK + (nt * 16 + c) * LS + q4 * 8), bq0, st[nt], 0, 0, 0);
      st[nt] = __builtin_amdgcn_mfma_f32_16x16x32_bf16(
          ld_frag(sK + (nt * 16 + c) * LS + 32 + q4 * 8), bq1, st[nt], 0, 0, 0);
    }

    // softmax numerators + P write (rows wave-private; no barrier needed)
    const bool diag = (jt == it);
    u16* prow = sP + il * LS;
#pragma unroll
    for (int nt = 0; nt < 4; ++nt) {
      float e0 = __builtin_amdgcn_exp2f(st[nt][0]);
      float e1 = __builtin_amdgcn_exp2f(st[nt][1]);
      float e2 = __builtin_amdgcn_exp2f(st[nt][2]);
      float e3 = __builtin_amdgcn_exp2f(st[nt][3]);
      if (diag) {  // mask j > i: j = nt*16+q4*4+rg, i = il = w*16+c
        const int jb = nt * 16 + q4 * 4;
        e0 = (jb + 0 > il) ? 0.f : e0;
        e1 = (jb + 1 > il) ? 0.f : e1;
        e2 = (jb + 2 > il) ? 0.f : e2;
        e3 = (jb + 3 > il) ? 0.f : e3;
      }
      lsum += (e0 + e1) + (e2 + e3);
      uint2 pk = {pack_bf2(e0, e1), pack_bf2(e2, e3)};
      *(uint2*)&prow[nt * 16 + q4 * 4] = pk;
    }

    // O^T += V^T @ P^T: A = V^T-frag (sV row d), B = P-frag (sP row i=il)
    bf16x8 bp0 = ld_frag(sP + il * LS + q4 * 8);
    bf16x8 bp1 = ld_frag(sP + il * LS + 32 + q4 * 8);
#pragma unroll
    for (int dt = 0; dt < 4; ++dt) {
      oacc[dt] = __builtin_amdgcn_mfma_f32_16x16x32_bf16(
          ld_frag(sV + (dt * 16 + c) * LS + q4 * 8), bp0, oacc[dt], 0, 0, 0);
      oacc[dt] = __builtin_amdgcn_mfma_f32_16x16x32_bf16(
          ld_frag(sV + (dt * 16 + c) * LS + 32 + q4 * 8), bp1, oacc[dt], 0, 0, 0);
    }
  }

  // full row sum for i = il: reduce across the 4 q4-groups (lanes c, c+16, c+32, c+48)
  lsum += __shfl_xor(lsum, 16);
  lsum += __shfl_xor(lsum, 32);
  const float linv = 1.f / lsum;

  // write out[b, t=it*64+il, h*64 + dt*16+q4*4+rg] bf16, packed b64 stores
  const int b_ = bh >> 4, h_ = bh & 15;
  const int t_ = it * 64 + il;
  u16* orow = outp + ((size_t)(b_ * 1024 + t_)) * 1024 + h_ * 64;
#pragma unroll
  for (int dt = 0; dt < 4; ++dt) {
    uint2 ok = {pack_bf2(oacc[dt][0] * linv, oacc[dt][1] * linv),
                pack_bf2(oacc[dt][2] * linv, oacc[dt][3] * linv)};
    *(uint2*)&orow[dt * 16 + q4 * 4] = ok;
  }
}

// ---------------------------------------------------------------------------
// Launch
// ---------------------------------------------------------------------------
extern "C" void kernel_launch(void* const* d_in, const int* in_sizes, int n_in,
                              void* d_out, int out_size, void* d_ws, size_t ws_size,
                              hipStream_t stream) {
  const float* x       = (const float*)d_in[0];
  const float* ln1_g   = (const float*)d_in[1];
  const float* ln1_b   = (const float*)d_in[2];
  const float* attn_w  = (const float*)d_in[3];
  const float* attn_b  = (const float*)d_in[4];
  const float* attn_pw = (const float*)d_in[5];
  const float* attn_pb = (const float*)d_in[6];
  const float* ln2_g   = (const float*)d_in[7];
  const float* ln2_b   = (const float*)d_in[8];
  const float* fc_w    = (const float*)d_in[9];
  const float* fc_b    = (const float*)d_in[10];
  const float* mlp_w   = (const float*)d_in[11];
  const float* mlp_b   = (const float*)d_in[12];
  float* out = (float*)d_out;

  // workspace layout (bf16 elements). mlpT first; then the region
  // [attn_wT | attn_pwT | fcT | hbuf] = (3072+1024+4096+8192)*1024*2 B
  // = 33,554,432 B, all dead by the time the MLP-proj GEMM runs -> it is
  // overlaid by the split-K fp32 partial (8192*1024*4 B = same size exactly).
  u16* ws = (u16*)d_ws;
  u16* mlpT     = ws;                         // 1024*4096
  u16* attn_wT  = mlpT + 1024 * 4096;         // 3072*1024
  u16* attn_pwT = attn_wT + 3072 * 1024;      // 1024*1024
  u16* fcT      = attn_pwT + 1024 * 1024;     // 4096*1024
  u16* hbuf     = fcT + 4096 * 1024;          // 8192*1024
  u16* kqv      = hbuf + 8192 * 1024;         // 8192*3072 (per-head layout)
  u16* attn_o   = kqv + (size_t)8192 * 3072;  // 8192*1024
  u16* mbuf     = kqv;                        // 8192*4096 (reuses kqv+attn_o)
  float* partial = (float*)attn_wT;           // 8192*1024 fp32 overlay

  dim3 tb(32, 8);
  transpose_bf16<<<dim3(96, 32),  tb, 0, stream>>>(attn_w,  attn_wT,  1024, 3072);
  transpose_bf16<<<dim3(32, 32),  tb, 0, stream>>>(attn_pw, attn_pwT, 1024, 1024);
  transpose_bf16<<<dim3(128, 32), tb, 0, stream>>>(fc_w,    fcT,      1024, 4096);
  transpose_bf16<<<dim3(32, 128), tb, 0, stream>>>(mlp_w,   mlpT,     4096, 1024);

  ln_kernel<<<8192, 256, 0, stream>>>(x, ln1_g, ln1_b, hbuf);

  gemm_kernel<EPI_KQV><<<dim3(24, 64), 256, 0, stream>>>(hbuf, attn_wT, attn_b, kqv,
                                                         nullptr, 8192, 3072, 1024);

  attn_kernel<<<dim3(128, 16), 256, 0, stream>>>(kqv, attn_o);

  gemm_kernel<EPI_RESID><<<dim3(8, 64), 256, 0, stream>>>(attn_o, attn_pwT, attn_pb, out,
                                                          x, 8192, 1024, 1024);

  ln_kernel<<<8192, 256, 0, stream>>>(out, ln2_g, ln2_b, hbuf);

  gemm_kernel<EPI_GELU><<<dim3(32, 64), 256, 0, stream>>>(hbuf, fcT, fc_b, mbuf,
                                                          nullptr, 8192, 4096, 1024);

  // split-K=2: 1024 blocks; z0 accumulates into out (+bias), z1 -> fp32 partial
  gemm_kernel<EPI_ADD><<<dim3(8, 64, 2), 256, 0, stream>>>(mbuf, mlpT, mlp_b, out,
                                                           partial, 8192, 1024, 4096);
  add_partial<<<8192, 256, 0, stream>>>(out, partial);
}

// Round 6
// 497.667 us; speedup vs baseline: 1.1990x; 1.1562x over previous
//
#include <hip/hip_runtime.h>
#include <stdint.h>

typedef unsigned short u16;
typedef __bf16 bf16x8 __attribute__((ext_vector_type(8)));
typedef float f32x4 __attribute__((ext_vector_type(4)));

#define DEVINL static __device__ __forceinline__

// fp32 -> bf16 round-to-nearest-even
DEVINL u16 f2bf(float f) {
  uint32_t u = __builtin_bit_cast(uint32_t, f);
  u += 0x7fffu + ((u >> 16) & 1u);
  return (u16)(u >> 16);
}

// pack two fp32 -> bf16x2 dword (round-half-up: +0x8000 then take hi16)
DEVINL uint32_t pack_bf2(float f0, float f1) {
  uint32_t u0 = __builtin_bit_cast(uint32_t, f0) + 0x8000u;
  uint32_t u1 = __builtin_bit_cast(uint32_t, f1) + 0x8000u;
  return __builtin_amdgcn_perm(u1, u0, 0x07060302u);  // [u1.hi16, u0.hi16]
}

DEVINL bf16x8 ld_frag(const u16* p) { return *(const bf16x8*)p; }

DEVINL void gld_lds16(const void* g, void* l) {
  __builtin_amdgcn_global_load_lds((const __attribute__((address_space(1))) void*)g,
                                   (__attribute__((address_space(3))) void*)l, 16, 0, 0);
}

// ---------------------------------------------------------------------------
// Weight convert+transpose: W fp32 (K,N) row-major -> Wt bf16 (N,K) row-major
// ---------------------------------------------------------------------------
__global__ __launch_bounds__(256)
void transpose_bf16(const float* __restrict__ W, u16* __restrict__ Wt, int K, int N) {
  __shared__ float tile[32][33];
  const int n0 = blockIdx.x * 32, k0 = blockIdx.y * 32;
  const int tx = threadIdx.x, ty = threadIdx.y;  // (32,8)
#pragma unroll
  for (int i = 0; i < 32; i += 8)
    tile[ty + i][tx] = W[(size_t)(k0 + ty + i) * N + n0 + tx];
  __syncthreads();
#pragma unroll
  for (int i = 0; i < 32; i += 8)
    Wt[(size_t)(n0 + ty + i) * K + k0 + tx] = f2bf(tile[tx][ty + i]);
}

// ---------------------------------------------------------------------------
// LayerNorm: fp32 (rows,1024) -> bf16, single pass (E[x^2]-mu^2), eps=1e-5
// ---------------------------------------------------------------------------
__global__ __launch_bounds__(256)
void ln_kernel(const float* __restrict__ x, const float* __restrict__ g,
               const float* __restrict__ b, u16* __restrict__ out) {
  __shared__ float red[8];
  const size_t row = blockIdx.x;
  const int tid = threadIdx.x;
  float4 v = ((const float4*)(x + row * 1024))[tid];
  float s = v.x + v.y + v.z + v.w;
  float s2 = v.x * v.x + v.y * v.y + v.z * v.z + v.w * v.w;
#pragma unroll
  for (int o = 32; o; o >>= 1) { s += __shfl_down(s, o); s2 += __shfl_down(s2, o); }
  const int w = tid >> 6;
  if ((tid & 63) == 0) { red[w * 2] = s; red[w * 2 + 1] = s2; }
  __syncthreads();
  const float S = red[0] + red[2] + red[4] + red[6];
  const float S2 = red[1] + red[3] + red[5] + red[7];
  const float mu = S * (1.f / 1024.f);
  const float var = S2 * (1.f / 1024.f) - mu * mu;
  const float rstd = rsqrtf(var + 1e-5f);
  float4 gv = ((const float4*)g)[tid];
  float4 bv = ((const float4*)b)[tid];
  ushort4 o;
  o.x = f2bf((v.x - mu) * rstd * gv.x + bv.x);
  o.y = f2bf((v.y - mu) * rstd * gv.y + bv.y);
  o.z = f2bf((v.z - mu) * rstd * gv.z + bv.z);
  o.w = f2bf((v.w - mu) * rstd * gv.w + bv.w);
  ((ushort4*)(out + row * 1024))[tid] = o;
}

// ---------------------------------------------------------------------------
// GEMM: C(M,N) = A(M,K) bf16 @ Bt(N,K)^T bf16, fp32 acc, fused epilogues.
// 128x128 tile, BK=32, 4 waves (2x2 of 64x64), 16x16x32 MFMA.
// SINGLE-BARRIER double-buffered K-loop: stage k+1 into the ping-pong buffer
// right after the barrier, compute k from the other — the vmcnt(0) at the top
// of the next iter waits on loads that had a full compute phase to land.
// ---------------------------------------------------------------------------
enum { EPI_KQV = 0, EPI_RESID = 1, EPI_GELU = 2, EPI_ADD = 3 };

template <int EPI>
__global__ __launch_bounds__(256)
void gemm_kernel(const u16* __restrict__ A, const u16* __restrict__ Bt,
                 const float* __restrict__ bias, void* __restrict__ outp,
                 const float* __restrict__ resid, int M, int N, int K) {
  __shared__ alignas(16) u16 sA[2][128 * 32];
  __shared__ alignas(16) u16 sB[2][128 * 32];
  const int tid = threadIdx.x;
  const int w = tid >> 6, l = tid & 63;
  const int q4 = l >> 4, c = l & 15;
  const int tm = blockIdx.y * 128, tn = blockIdx.x * 128;
  const int mh = (w >> 1) * 64, nh = (w & 1) * 64;

  f32x4 acc[4][4] = {};

  // staging: 8 chunks of 1KB each per matrix (16 rows x 32 cols); wave w owns
  // chunks 2w, 2w+1 of each. LDS dest is wave-uniform base + lane*16.
  const int srow = l >> 2;           // 0..15 row within chunk
  const int scol = (l & 3) * 8;      // elem col within row
  const u16* gA0 = A + (size_t)(tm + (w * 2) * 16 + srow) * K + scol;
  const u16* gA1 = A + (size_t)(tm + (w * 2 + 1) * 16 + srow) * K + scol;
  const u16* gB0 = Bt + (size_t)(tn + (w * 2) * 16 + srow) * K + scol;
  const u16* gB1 = Bt + (size_t)(tn + (w * 2 + 1) * 16 + srow) * K + scol;
  const int cA0 = (w * 2) * 512, cA1 = (w * 2 + 1) * 512;

  const int nIters = K / 32;
#define STAGE(buf, k0)                          \
  do {                                          \
    gld_lds16(gA0 + (k0), &sA[buf][cA0]);       \
    gld_lds16(gA1 + (k0), &sA[buf][cA1]);       \
    gld_lds16(gB0 + (k0), &sB[buf][cA0]);       \
    gld_lds16(gB1 + (k0), &sB[buf][cA1]);       \
  } while (0)

  STAGE(0, 0);
  for (int i = 0; i < nIters; ++i) {
    const int cur = i & 1;
    asm volatile("s_waitcnt vmcnt(0)" ::: "memory");  // buf[cur] staged
    __syncthreads();  // all waves done reading buf[cur^1] (iter i-1) + see stage
    if (i + 1 < nIters) STAGE(cur ^ 1, (i + 1) * 32);  // overlaps compute below
    const u16* bA = sA[cur];
    const u16* bB = sB[cur];
    bf16x8 af[4], bfv[4];
#pragma unroll
    for (int mt = 0; mt < 4; ++mt) af[mt] = ld_frag(bA + (mh + mt * 16 + c) * 32 + q4 * 8);
#pragma unroll
    for (int nt = 0; nt < 4; ++nt) bfv[nt] = ld_frag(bB + (nh + nt * 16 + c) * 32 + q4 * 8);
#pragma unroll
    for (int mt = 0; mt < 4; ++mt)
#pragma unroll
      for (int nt = 0; nt < 4; ++nt)
        acc[mt][nt] = __builtin_amdgcn_mfma_f32_16x16x32_bf16(af[mt], bfv[nt], acc[mt][nt], 0, 0, 0);
  }
#undef STAGE

  // epilogue: C row = tm+mh+mt*16+q4*4+reg, col = tn+nh+nt*16+c
#pragma unroll
  for (int mt = 0; mt < 4; ++mt) {
#pragma unroll
    for (int nt = 0; nt < 4; ++nt) {
      const int col = tn + nh + nt * 16 + c;
      const float bcol = bias[col];
#pragma unroll
      for (int rg = 0; rg < 4; ++rg) {
        const int row = tm + mh + mt * 16 + q4 * 4 + rg;
        float val = acc[mt][nt][rg] + bcol;
        if constexpr (EPI == EPI_KQV) {
          // scatter to per-head layout [b,h][s][...]; s: 0=k (flash-Q, pre-scaled
          // by 0.125*log2e for exp2-domain softmax), 1=q (t,d), 2=v stored (d,t)
          const int bb = row >> 10, t = row & 1023;
          const int s = col >> 10, rem = col & 1023;
          const int hh = rem >> 6, d = rem & 63;
          if (s == 0) val *= 0.18033688011112042f;  // 0.125 * log2(e)
          const size_t base = ((size_t)((bb * 16 + hh) * 3 + s)) << 16;
          const size_t idx = (s == 2) ? base + (size_t)d * 1024 + t : base + (size_t)t * 64 + d;
          ((u16*)outp)[idx] = f2bf(val);
        } else if constexpr (EPI == EPI_RESID) {
          const size_t idx = (size_t)row * 1024 + col;
          ((float*)outp)[idx] = val + resid[idx];
        } else if constexpr (EPI == EPI_GELU) {
          // tanh-approx GELU via single exp2: x*sigmoid(1.5957691(x+0.044715x^3))
          const float x2 = val * val;
          const float t = __builtin_fmaf(x2, -0.102952445f, -2.30221235f);  // *log2e folded
          const float e = __builtin_amdgcn_exp2f(val * t);
          const float ge = val * __builtin_amdgcn_rcpf(1.0f + e);
          ((u16*)outp)[(size_t)row * N + col] = f2bf(ge);
        } else {  // EPI_ADD: accumulate into fp32 out (sole writer)
          const size_t idx = (size_t)row * 1024 + col;
          ((float*)outp)[idx] += val;
        }
      }
    }
  }
}

// ---------------------------------------------------------------------------
// Flash attention, causal, fixed-max softmax in exp2 domain.
// Computes S^T = fK_tile @ fQ_tile^T and O^T = V^T_tile @ P^T so each lane owns
// one full i-row (i = w*16 + c): per-lane scalar lsum, j-contiguous P writes
// (ds_write_b64), no online-max machinery, no P barrier (wave-private rows).
// Roles: flash-Q = reference k (s=0, pre-scaled), flash-K = q (s=1), V = s=2 (D,T).
// ---------------------------------------------------------------------------
__global__ __launch_bounds__(256)
void attn_kernel(const u16* __restrict__ kqv, u16* __restrict__ outp) {
  constexpr int LS = 72;  // padded stride: 144B rows, 16B aligned, 2-way max conflicts
  __shared__ alignas(16) u16 sP[64 * LS];  // holds Q tile at start, then P (aliased)
  __shared__ alignas(16) u16 sK[64 * LS];
  __shared__ alignas(16) u16 sV[64 * LS];  // V^T tile: row=d, col=j
  const int bh = blockIdx.x;
  const int it = (int)gridDim.y - 1 - (int)blockIdx.y;  // longest blocks dispatch first
  const int tid = threadIdx.x;
  const int w = tid >> 6, l = tid & 63, q4 = l >> 4, c = l & 15;
  const int il = w * 16 + c;  // this lane's i-row within the 64-row tile
  const size_t hb = (size_t)bh * 3 * 65536;
  const u16* qbase = kqv + hb;               // flash-Q (T,D), pre-scaled
  const u16* kbase = kqv + hb + 65536;       // flash-K (T,D)
  const u16* vbase = kqv + hb + 2 * 65536;   // V^T (D,T)

  // stage Q tile into sP (aliased; consumed once after first barrier)
  const int sr = tid >> 3, sc = (tid & 7) * 8;        // staging row/col A
  const int sr2 = sr + 32;                            // staging row B
  *(int4*)&sP[sr * LS + sc] = *(const int4*)(qbase + (size_t)(it * 64 + sr) * 64 + sc);
  *(int4*)&sP[sr2 * LS + sc] = *(const int4*)(qbase + (size_t)(it * 64 + sr2) * 64 + sc);

  f32x4 oacc[4] = {};   // O^T: oacc[dt][rg] = O[i=il][d=dt*16+q4*4+rg]
  float lsum = 0.f;     // per-lane partial row-sum for row i=il
  bf16x8 bq0, bq1;      // loop-invariant Q B-frags

  for (int jt = 0; jt <= it; ++jt) {
    if (jt) __syncthreads();  // prior iter's sK/sV reads done before overwrite
    *(int4*)&sK[sr * LS + sc] = *(const int4*)(kbase + (size_t)(jt * 64 + sr) * 64 + sc);
    *(int4*)&sK[sr2 * LS + sc] = *(const int4*)(kbase + (size_t)(jt * 64 + sr2) * 64 + sc);
    *(int4*)&sV[sr * LS + sc] = *(const int4*)(vbase + (size_t)sr * 1024 + jt * 64 + sc);
    *(int4*)&sV[sr2 * LS + sc] = *(const int4*)(vbase + (size_t)sr2 * 1024 + jt * 64 + sc);
    __syncthreads();
    if (jt == 0) {  // Q frags: B[k=d][n=i]: lane reads fQ[i=il][d=q4*8..]
      bq0 = ld_frag(sP + il * LS + q4 * 8);
      bq1 = ld_frag(sP + il * LS + 32 + q4 * 8);
    }

    // S^T = fK @ fQ^T: st[nt] row j=nt*16+q4*4+rg, col i=il (values in log2 domain)
    f32x4 st[4] = {};
#pragma unroll
    for (int nt = 0; nt < 4; ++nt) {
      st[nt] = __builtin_amdgcn_mfma_f32_16x16x32_bf16(
          ld_frag(sK + (nt * 16 + c) * LS + q4 * 8), bq0, st[nt], 0, 0, 0);
      st[nt] = __builtin_amdgcn_mfma_f32_16x16x32_bf16(
          ld_frag(sK + (nt * 16 + c) * LS + 32 + q4 * 8), bq1, st[nt], 0, 0, 0);
    }

    // softmax numerators + P write (rows wave-private; no barrier needed)
    const bool diag = (jt == it);
    u16* prow = sP + il * LS;
#pragma unroll
    for (int nt = 0; nt < 4; ++nt) {
      float e0 = __builtin_amdgcn_exp2f(st[nt][0]);
      float e1 = __builtin_amdgcn_exp2f(st[nt][1]);
      float e2 = __builtin_amdgcn_exp2f(st[nt][2]);
      float e3 = __builtin_amdgcn_exp2f(st[nt][3]);
      if (diag) {  // mask j > i: j = nt*16+q4*4+rg, i = il = w*16+c
        const int jb = nt * 16 + q4 * 4;
        e0 = (jb + 0 > il) ? 0.f : e0;
        e1 = (jb + 1 > il) ? 0.f : e1;
        e2 = (jb + 2 > il) ? 0.f : e2;
        e3 = (jb + 3 > il) ? 0.f : e3;
      }
      lsum += (e0 + e1) + (e2 + e3);
      uint2 pk = {pack_bf2(e0, e1), pack_bf2(e2, e3)};
      *(uint2*)&prow[nt * 16 + q4 * 4] = pk;
    }

    // O^T += V^T @ P^T: A = V^T-frag (sV row d), B = P-frag (sP row i=il)
    bf16x8 bp0 = ld_frag(sP + il * LS + q4 * 8);
    bf16x8 bp1 = ld_frag(sP + il * LS + 32 + q4 * 8);
#pragma unroll
    for (int dt = 0; dt < 4; ++dt) {
      oacc[dt] = __builtin_amdgcn_mfma_f32_16x16x32_bf16(
          ld_frag(sV + (dt * 16 + c) * LS + q4 * 8), bp0, oacc[dt], 0, 0, 0);
      oacc[dt] = __builtin_amdgcn_mfma_f32_16x16x32_bf16(
          ld_frag(sV + (dt * 16 + c) * LS + 32 + q4 * 8), bp1, oacc[dt], 0, 0, 0);
    }
  }

  // full row sum for i = il: reduce across the 4 q4-groups (lanes c, c+16, c+32, c+48)
  lsum += __shfl_xor(lsum, 16);
  lsum += __shfl_xor(lsum, 32);
  const float linv = 1.f / lsum;

  // write out[b, t=it*64+il, h*64 + dt*16+q4*4+rg] bf16, packed b64 stores
  const int b_ = bh >> 4, h_ = bh & 15;
  const int t_ = it * 64 + il;
  u16* orow = outp + ((size_t)(b_ * 1024 + t_)) * 1024 + h_ * 64;
#pragma unroll
  for (int dt = 0; dt < 4; ++dt) {
    uint2 ok = {pack_bf2(oacc[dt][0] * linv, oacc[dt][1] * linv),
                pack_bf2(oacc[dt][2] * linv, oacc[dt][3] * linv)};
    *(uint2*)&orow[dt * 16 + q4 * 4] = ok;
  }
}

// ---------------------------------------------------------------------------
// Launch
// ---------------------------------------------------------------------------
extern "C" void kernel_launch(void* const* d_in, const int* in_sizes, int n_in,
                              void* d_out, int out_size, void* d_ws, size_t ws_size,
                              hipStream_t stream) {
  const float* x       = (const float*)d_in[0];
  const float* ln1_g   = (const float*)d_in[1];
  const float* ln1_b   = (const float*)d_in[2];
  const float* attn_w  = (const float*)d_in[3];
  const float* attn_b  = (const float*)d_in[4];
  const float* attn_pw = (const float*)d_in[5];
  const float* attn_pb = (const float*)d_in[6];
  const float* ln2_g   = (const float*)d_in[7];
  const float* ln2_b   = (const float*)d_in[8];
  const float* fc_w    = (const float*)d_in[9];
  const float* fc_b    = (const float*)d_in[10];
  const float* mlp_w   = (const float*)d_in[11];
  const float* mlp_b   = (const float*)d_in[12];
  float* out = (float*)d_out;

  // workspace layout (bf16 elements)
  u16* ws = (u16*)d_ws;
  u16* mlpT     = ws;                         // 1024*4096
  u16* attn_wT  = mlpT + 1024 * 4096;         // 3072*1024
  u16* attn_pwT = attn_wT + 3072 * 1024;      // 1024*1024
  u16* fcT      = attn_pwT + 1024 * 1024;     // 4096*1024
  u16* hbuf     = fcT + 4096 * 1024;          // 8192*1024
  u16* kqv      = hbuf + 8192 * 1024;         // 8192*3072 (per-head layout)
  u16* attn_o   = kqv + (size_t)8192 * 3072;  // 8192*1024
  u16* mbuf     = kqv;                        // 8192*4096 (reuses kqv+attn_o)

  dim3 tb(32, 8);
  transpose_bf16<<<dim3(96, 32),  tb, 0, stream>>>(attn_w,  attn_wT,  1024, 3072);
  transpose_bf16<<<dim3(32, 32),  tb, 0, stream>>>(attn_pw, attn_pwT, 1024, 1024);
  transpose_bf16<<<dim3(128, 32), tb, 0, stream>>>(fc_w,    fcT,      1024, 4096);
  transpose_bf16<<<dim3(32, 128), tb, 0, stream>>>(mlp_w,   mlpT,     4096, 1024);

  ln_kernel<<<8192, 256, 0, stream>>>(x, ln1_g, ln1_b, hbuf);

  gemm_kernel<EPI_KQV><<<dim3(24, 64), 256, 0, stream>>>(hbuf, attn_wT, attn_b, kqv,
                                                         nullptr, 8192, 3072, 1024);

  attn_kernel<<<dim3(128, 16), 256, 0, stream>>>(kqv, attn_o);

  gemm_kernel<EPI_RESID><<<dim3(8, 64), 256, 0, stream>>>(attn_o, attn_pwT, attn_pb, out,
                                                          x, 8192, 1024, 1024);

  ln_kernel<<<8192, 256, 0, stream>>>(out, ln2_g, ln2_b, hbuf);

  gemm_kernel<EPI_GELU><<<dim3(32, 64), 256, 0, stream>>>(hbuf, fcT, fc_b, mbuf,
                                                          nullptr, 8192, 4096, 1024);

  gemm_kernel<EPI_ADD><<<dim3(8, 64), 256, 0, stream>>>(mbuf, mlpT, mlp_b, out,
                                                        nullptr, 8192, 1024, 4096);
}